// Round 1
// baseline (6762.225 us; speedup 1.0000x reference)
//
#include <hip/hip_runtime.h>

// ---------------------------------------------------------------------------
// HeadsSelection: emb-gather -> 2x bidirectional LSTM -> additive attention
// S=256, B=16, V=20000, E=512, H=256, L=2, HM=128
// Round 1: full fp32, correctness-first.
//   - input gates precomputed as big GEMMs (time-parallel)
//   - recurrence: 16 WGs/dir, weight-stationary in LDS, h exchanged via
//     agent-scope atomics + per-dir monotonic barrier (per-XCD L2 non-coherent)
// ---------------------------------------------------------------------------

#define S_    256
#define B_    16
#define E_    512
#define H_    256
#define HM_   128
#define M_    4096   // S*B

__device__ __forceinline__ float sigm(float x) { return 1.f / (1.f + expf(-x)); }

// ---------------------------------------------------------------- gather ----
__global__ void k_gather(const int* __restrict__ concepts, const float* __restrict__ emb,
                         float* __restrict__ X) {
  int m = blockIdx.x;                       // m = s*16 + b
  int tok = concepts[m];
  const float4* src = reinterpret_cast<const float4*>(emb + (size_t)tok * E_);
  float4* dst = reinterpret_cast<float4*>(X + (size_t)m * E_);
  for (int i = threadIdx.x; i < E_ / 4; i += blockDim.x) dst[i] = src[i];
}

// ------------------------------------------------------------------ GEMM ----
// C[m][n] = sum_k A[m][k] * W[n][k] + bias[n]
// TRANS: store C[n*M + m] (for Gin, so recurrence reads contiguous b-vectors)
// else : store C[m*N + n] (for attention projections)
template <bool TRANS>
__global__ __launch_bounds__(256) void k_gemm(const float* __restrict__ A,
                                              const float* __restrict__ W,
                                              const float* __restrict__ bias,
                                              float* __restrict__ C,
                                              int M, int N, int K) {
  __shared__ __align__(16) float As[16][132];
  __shared__ __align__(16) float Ws[16][132];
  const int bm = blockIdx.x * 128, bn = blockIdx.y * 128;
  const int tid = threadIdx.x;
  const int tm = (tid >> 4) * 8, tn = (tid & 15) * 8;
  float acc[8][8];
#pragma unroll
  for (int i = 0; i < 8; i++)
#pragma unroll
    for (int j = 0; j < 8; j++) acc[i][j] = 0.f;

  const int lr = tid >> 1, lk = (tid & 1) * 8;
  for (int k0 = 0; k0 < K; k0 += 16) {
    float4 a0 = *(const float4*)(A + (size_t)(bm + lr) * K + k0 + lk);
    float4 a1 = *(const float4*)(A + (size_t)(bm + lr) * K + k0 + lk + 4);
    float4 w0 = *(const float4*)(W + (size_t)(bn + lr) * K + k0 + lk);
    float4 w1 = *(const float4*)(W + (size_t)(bn + lr) * K + k0 + lk + 4);
    As[lk + 0][lr] = a0.x; As[lk + 1][lr] = a0.y; As[lk + 2][lr] = a0.z; As[lk + 3][lr] = a0.w;
    As[lk + 4][lr] = a1.x; As[lk + 5][lr] = a1.y; As[lk + 6][lr] = a1.z; As[lk + 7][lr] = a1.w;
    Ws[lk + 0][lr] = w0.x; Ws[lk + 1][lr] = w0.y; Ws[lk + 2][lr] = w0.z; Ws[lk + 3][lr] = w0.w;
    Ws[lk + 4][lr] = w1.x; Ws[lk + 5][lr] = w1.y; Ws[lk + 6][lr] = w1.z; Ws[lk + 7][lr] = w1.w;
    __syncthreads();
#pragma unroll
    for (int k = 0; k < 16; k++) {
      float4 av0 = *(const float4*)&As[k][tm];
      float4 av1 = *(const float4*)&As[k][tm + 4];
      float4 wv0 = *(const float4*)&Ws[k][tn];
      float4 wv1 = *(const float4*)&Ws[k][tn + 4];
      float a[8] = {av0.x, av0.y, av0.z, av0.w, av1.x, av1.y, av1.z, av1.w};
      float w[8] = {wv0.x, wv0.y, wv0.z, wv0.w, wv1.x, wv1.y, wv1.z, wv1.w};
#pragma unroll
      for (int i = 0; i < 8; i++)
#pragma unroll
        for (int j = 0; j < 8; j++) acc[i][j] += a[i] * w[j];
    }
    __syncthreads();
  }

  if (TRANS) {
#pragma unroll
    for (int j = 0; j < 8; j++) {
      float bv = bias ? bias[bn + tn + j] : 0.f;
      float4 v0 = make_float4(acc[0][j] + bv, acc[1][j] + bv, acc[2][j] + bv, acc[3][j] + bv);
      float4 v1 = make_float4(acc[4][j] + bv, acc[5][j] + bv, acc[6][j] + bv, acc[7][j] + bv);
      *(float4*)(C + (size_t)(bn + tn + j) * M + bm + tm) = v0;
      *(float4*)(C + (size_t)(bn + tn + j) * M + bm + tm + 4) = v1;
    }
  } else {
    float bv[8];
#pragma unroll
    for (int j = 0; j < 8; j++) bv[j] = bias ? bias[bn + tn + j] : 0.f;
#pragma unroll
    for (int i = 0; i < 8; i++) {
      float4 v0 = make_float4(acc[i][0] + bv[0], acc[i][1] + bv[1], acc[i][2] + bv[2], acc[i][3] + bv[3]);
      float4 v1 = make_float4(acc[i][4] + bv[4], acc[i][5] + bv[5], acc[i][6] + bv[6], acc[i][7] + bv[7]);
      *(float4*)(C + (size_t)(bm + tm + i) * N + bn + tn) = v0;
      *(float4*)(C + (size_t)(bm + tm + i) * N + bn + tn + 4) = v1;
    }
  }
}

// ------------------------------------------------------------- LSTM layer ----
// Grid: 32 WGs = dir(2) x g(16). WG (d,g) owns h-units [g*16, g*16+16) i.e.
// gate rows q*256 + g*16 + j for q=0..3 (64 rows), ALL 16 batches.
// Weights LDS-stationary (64KB). h state exchanged via Hbuf (agent-scope).
// Gin layout: [n=d*1024+row][m=t*16+b]  (TRANS gemm output)
// Hout layout: [(t*16+b)*512 + d*256 + unit]
// Hbuf layout: [d][parity][unit][b]  (2*2*256*16 floats)
__global__ __launch_bounds__(512) void k_lstm(const float* __restrict__ Gin,
                                              const float* __restrict__ whh,
                                              float* __restrict__ Hout,
                                              float* __restrict__ Hbuf,
                                              int* __restrict__ bar) {
  const int d = blockIdx.x >> 4;
  const int g = blockIdx.x & 15;
  const int tid = threadIdx.x;
  __shared__ float whT[256][65];                 // whT[k][local_row]
  __shared__ __align__(16) float hs[256][16];    // h_prev [k][b]
  __shared__ float gacc[8][64][17];              // partial sums per k-chunk wave
  __shared__ float gsum[64][17];                 // reduced gates [local_row][b]

  // load recurrent weights (transposed) into LDS, once
  for (int idx = tid; idx < 64 * 256; idx += 512) {
    int lr = idx >> 8, k = idx & 255;
    int grow = ((lr >> 4) << 8) + (g << 4) + (lr & 15);
    whT[k][lr] = whh[(size_t)((d << 10) + grow) * 256 + k];
  }
  float* hsf = &hs[0][0];
  float c_reg = 0.f;                             // cell state for (u=tid>>4, b=tid&15), tid<256
  int* cnt = bar + d;
  const int wv = tid >> 6, r = tid & 63;
  const int kb = wv * 32;
  const int ub = tid >> 4;                       // 0..31
  const int bb = tid & 15;
  __syncthreads();

  for (int it = 0; it < 256; ++it) {
    const int step = d ? (255 - it) : it;

    // ---- stage h_prev into LDS (coherent loads: WGs span XCDs) ----
    if (it == 0) {
      for (int i = tid; i < 4096; i += 512) hsf[i] = 0.f;
    } else {
      float* src = Hbuf + (size_t)((d << 1) + ((it - 1) & 1)) * 4096;
      for (int i = tid; i < 4096; i += 512)
        hsf[i] = __hip_atomic_load(src + i, __ATOMIC_RELAXED, __HIP_MEMORY_SCOPE_AGENT);
    }
    __syncthreads();

    // ---- partial matvec: wave wv covers k in [kb, kb+32) ----
    float acc[16];
#pragma unroll
    for (int b = 0; b < 16; b++) acc[b] = 0.f;
#pragma unroll 4
    for (int k = kb; k < kb + 32; ++k) {
      float w = whT[k][r];
      const float4* hp = reinterpret_cast<const float4*>(&hs[k][0]);
      float4 h0 = hp[0], h1 = hp[1], h2 = hp[2], h3 = hp[3];
      acc[0]  += w * h0.x; acc[1]  += w * h0.y; acc[2]  += w * h0.z; acc[3]  += w * h0.w;
      acc[4]  += w * h1.x; acc[5]  += w * h1.y; acc[6]  += w * h1.z; acc[7]  += w * h1.w;
      acc[8]  += w * h2.x; acc[9]  += w * h2.y; acc[10] += w * h2.z; acc[11] += w * h2.w;
      acc[12] += w * h3.x; acc[13] += w * h3.y; acc[14] += w * h3.z; acc[15] += w * h3.w;
    }
#pragma unroll
    for (int b = 0; b < 16; b++) gacc[wv][r][b] = acc[b];
    __syncthreads();

    // ---- reduce 8 partials + Gin ----
#pragma unroll
    for (int ii = 0; ii < 2; ++ii) {
      int lr = (ub << 1) + ii;
      float s = 0.f;
#pragma unroll
      for (int p = 0; p < 8; p++) s += gacc[p][lr][bb];
      int grow = ((lr >> 4) << 8) + (g << 4) + (lr & 15);
      s += Gin[(size_t)((d << 10) + grow) * 4096 + (step << 4) + bb];
      gsum[lr][bb] = s;
    }
    __syncthreads();

    // ---- nonlinearity + state update (256 threads: u x b) ----
    if (tid < 256) {
      int u = ub;  // 0..15
      float ig = gsum[u][bb], fg = gsum[16 + u][bb], gg = gsum[32 + u][bb], og = gsum[48 + u][bb];
      float ct = sigm(fg) * c_reg + sigm(ig) * tanhf(gg);
      c_reg = ct;
      float h = sigm(og) * tanhf(ct);
      int unit = (g << 4) + u;
      __hip_atomic_store(Hbuf + (size_t)((d << 1) + (it & 1)) * 4096 + (unit << 4) + bb, h,
                         __ATOMIC_RELAXED, __HIP_MEMORY_SCOPE_AGENT);
      Hout[(size_t)((step << 4) + bb) * 512 + (d << 8) + unit] = h;
    }
    __threadfence();
    __syncthreads();

    // ---- per-direction barrier (monotonic counter, 16 arrivals/step) ----
    if (tid == 0) {
      __hip_atomic_fetch_add(cnt, 1, __ATOMIC_RELEASE, __HIP_MEMORY_SCOPE_AGENT);
      while (__hip_atomic_load(cnt, __ATOMIC_ACQUIRE, __HIP_MEMORY_SCOPE_AGENT) < 16 * (it + 1))
        __builtin_amdgcn_s_sleep(2);
    }
    __syncthreads();
  }
}

// ------------------------------------------------------------- attention ----
// scores[b][i][j] = sum_h va[h]*tanh(P[i*16+b][h] + Cc[j*16+b][h])
// out[0 .. 1M)   = scores (float)
// out[1M .. 2M)  = predictions (float 0/1) ; sigmoid(x)>=0.5 <=> x>=0
__global__ __launch_bounds__(256) void k_attn(const float* __restrict__ P,
                                              const float* __restrict__ Cc,
                                              const float* __restrict__ va,
                                              float* __restrict__ out) {
  const int b = blockIdx.x & 15, i = blockIdx.x >> 4;
  __shared__ float pv[128], vv[128];
  const int t = threadIdx.x;
  if (t < 128) {
    pv[t] = P[(size_t)((i << 4) + b) * 128 + t];
    vv[t] = va[t];
  }
  __syncthreads();
  const float4* c4 = reinterpret_cast<const float4*>(Cc + (size_t)((t << 4) + b) * 128);
  float acc = 0.f;
#pragma unroll 8
  for (int hh = 0; hh < 32; ++hh) {
    float4 cv = c4[hh];
    int h = hh << 2;
    acc += vv[h]     * tanhf(pv[h]     + cv.x);
    acc += vv[h + 1] * tanhf(pv[h + 1] + cv.y);
    acc += vv[h + 2] * tanhf(pv[h + 2] + cv.z);
    acc += vv[h + 3] * tanhf(pv[h + 3] + cv.w);
  }
  size_t o = ((size_t)b << 16) + ((size_t)i << 8) + (size_t)t;
  out[o] = acc;
  out[(1u << 20) + o] = (acc >= 0.f) ? 1.f : 0.f;
}

// --------------------------------------------------------------- launch ----
extern "C" void kernel_launch(void* const* d_in, const int* in_sizes, int n_in,
                              void* d_out, int out_size, void* d_ws, size_t ws_size,
                              hipStream_t stream) {
  const int*   concepts = (const int*)d_in[0];
  // d_in[1] = concepts_lengths (all == S, unused)
  const float* emb  = (const float*)d_in[2];
  const float* w_ih = (const float*)d_in[3];   // [2][2][1024][512]
  const float* w_hh = (const float*)d_in[4];   // [2][2][1024][256]
  const float* bias = (const float*)d_in[5];   // [2][2][1024]
  const float* Ua   = (const float*)d_in[6];   // [128][512]
  const float* Wa   = (const float*)d_in[7];   // [128][512]
  const float* va   = (const float*)d_in[8];   // [1][128]
  float* out = (float*)d_out;
  float* ws  = (float*)d_ws;

  constexpr size_t OFF_X   = 0;
  constexpr size_t OFF_G   = OFF_X  + (size_t)M_ * E_;        //  2,097,152
  constexpr size_t OFF_H0  = OFF_G  + (size_t)M_ * 2048;      // 10,485,760
  constexpr size_t OFF_H1  = OFF_H0 + (size_t)M_ * 512;
  constexpr size_t OFF_P   = OFF_H1 + (size_t)M_ * 512;
  constexpr size_t OFF_C   = OFF_P  + (size_t)M_ * HM_;
  constexpr size_t OFF_HB  = OFF_C  + (size_t)M_ * HM_;
  constexpr size_t OFF_BAR = OFF_HB + 2 * 2 * 256 * 16;

  float* X  = ws + OFF_X;
  float* G  = ws + OFF_G;
  float* H0 = ws + OFF_H0;
  float* H1 = ws + OFF_H1;
  float* Pm = ws + OFF_P;
  float* Cm = ws + OFF_C;
  float* Hb = ws + OFF_HB;
  int*   bar = (int*)(ws + OFF_BAR);

  hipMemsetAsync(bar, 0, 4 * sizeof(int), stream);

  k_gather<<<M_, 128, 0, stream>>>(concepts, emb, X);

  // layer 0
  k_gemm<true><<<dim3(32, 16), 256, 0, stream>>>(X, w_ih, bias, G, M_, 2048, 512);
  k_lstm<<<32, 512, 0, stream>>>(G, w_hh, H0, Hb, bar);

  // layer 1
  k_gemm<true><<<dim3(32, 16), 256, 0, stream>>>(H0, w_ih + (size_t)2048 * 512, bias + 2048,
                                                 G, M_, 2048, 512);
  k_lstm<<<32, 512, 0, stream>>>(G, w_hh + (size_t)2048 * 256, H1, Hb, bar + 2);

  // attention projections
  k_gemm<false><<<dim3(32, 1), 256, 0, stream>>>(H1, Ua, nullptr, Pm, M_, HM_, 512);
  k_gemm<false><<<dim3(32, 1), 256, 0, stream>>>(H1, Wa, nullptr, Cm, M_, HM_, 512);

  // fused pairwise scores + predictions
  k_attn<<<M_, 256, 0, stream>>>(Pm, Cm, va, out);
}

// Round 2
// 3950.546 us; speedup vs baseline: 1.7117x; 1.7117x over previous
//
#include <hip/hip_runtime.h>

// ---------------------------------------------------------------------------
// HeadsSelection: emb-gather -> 2x bidirectional LSTM -> additive attention
// S=256, B=16, V=20000, E=512, H=256, L=2, HM=128
// Round 2: relaxed-atomic LLC exchange for the recurrence.
//   - NO threadfence / release / acquire in the hot loop (those emit
//     buffer_wbl2 / buffer_inv on gfx950 = full L2 walks; R1 showed 12us/step)
//   - writer: relaxed sc1 h-stores, __syncthreads (drains vmcnt before
//     s_barrier), then ONE relaxed per-WG tag-word publish
//   - reader: 16 threads poll 16 tag words relaxed, barrier, relaxed loads
// ---------------------------------------------------------------------------

#define S_    256
#define B_    16
#define E_    512
#define H_    256
#define HM_   128
#define M_    4096   // S*B

__device__ __forceinline__ float sigm(float x) { return 1.f / (1.f + expf(-x)); }

// ---------------------------------------------------------------- gather ----
__global__ void k_gather(const int* __restrict__ concepts, const float* __restrict__ emb,
                         float* __restrict__ X) {
  int m = blockIdx.x;                       // m = s*16 + b
  int tok = concepts[m];
  const float4* src = reinterpret_cast<const float4*>(emb + (size_t)tok * E_);
  float4* dst = reinterpret_cast<float4*>(X + (size_t)m * E_);
  for (int i = threadIdx.x; i < E_ / 4; i += blockDim.x) dst[i] = src[i];
}

// ------------------------------------------------------------------ GEMM ----
// C[m][n] = sum_k A[m][k] * W[n][k] + bias[n]
// TRANS: store C[n*M + m] (for Gin, so recurrence reads contiguous b-vectors)
// else : store C[m*N + n] (for attention projections)
template <bool TRANS>
__global__ __launch_bounds__(256) void k_gemm(const float* __restrict__ A,
                                              const float* __restrict__ W,
                                              const float* __restrict__ bias,
                                              float* __restrict__ C,
                                              int M, int N, int K) {
  __shared__ __align__(16) float As[16][132];
  __shared__ __align__(16) float Ws[16][132];
  const int bm = blockIdx.x * 128, bn = blockIdx.y * 128;
  const int tid = threadIdx.x;
  const int tm = (tid >> 4) * 8, tn = (tid & 15) * 8;
  float acc[8][8];
#pragma unroll
  for (int i = 0; i < 8; i++)
#pragma unroll
    for (int j = 0; j < 8; j++) acc[i][j] = 0.f;

  const int lr = tid >> 1, lk = (tid & 1) * 8;
  for (int k0 = 0; k0 < K; k0 += 16) {
    float4 a0 = *(const float4*)(A + (size_t)(bm + lr) * K + k0 + lk);
    float4 a1 = *(const float4*)(A + (size_t)(bm + lr) * K + k0 + lk + 4);
    float4 w0 = *(const float4*)(W + (size_t)(bn + lr) * K + k0 + lk);
    float4 w1 = *(const float4*)(W + (size_t)(bn + lr) * K + k0 + lk + 4);
    As[lk + 0][lr] = a0.x; As[lk + 1][lr] = a0.y; As[lk + 2][lr] = a0.z; As[lk + 3][lr] = a0.w;
    As[lk + 4][lr] = a1.x; As[lk + 5][lr] = a1.y; As[lk + 6][lr] = a1.z; As[lk + 7][lr] = a1.w;
    Ws[lk + 0][lr] = w0.x; Ws[lk + 1][lr] = w0.y; Ws[lk + 2][lr] = w0.z; Ws[lk + 3][lr] = w0.w;
    Ws[lk + 4][lr] = w1.x; Ws[lk + 5][lr] = w1.y; Ws[lk + 6][lr] = w1.z; Ws[lk + 7][lr] = w1.w;
    __syncthreads();
#pragma unroll
    for (int k = 0; k < 16; k++) {
      float4 av0 = *(const float4*)&As[k][tm];
      float4 av1 = *(const float4*)&As[k][tm + 4];
      float4 wv0 = *(const float4*)&Ws[k][tn];
      float4 wv1 = *(const float4*)&Ws[k][tn + 4];
      float a[8] = {av0.x, av0.y, av0.z, av0.w, av1.x, av1.y, av1.z, av1.w};
      float w[8] = {wv0.x, wv0.y, wv0.z, wv0.w, wv1.x, wv1.y, wv1.z, wv1.w};
#pragma unroll
      for (int i = 0; i < 8; i++)
#pragma unroll
        for (int j = 0; j < 8; j++) acc[i][j] += a[i] * w[j];
    }
    __syncthreads();
  }

  if (TRANS) {
#pragma unroll
    for (int j = 0; j < 8; j++) {
      float bv = bias ? bias[bn + tn + j] : 0.f;
      float4 v0 = make_float4(acc[0][j] + bv, acc[1][j] + bv, acc[2][j] + bv, acc[3][j] + bv);
      float4 v1 = make_float4(acc[4][j] + bv, acc[5][j] + bv, acc[6][j] + bv, acc[7][j] + bv);
      *(float4*)(C + (size_t)(bn + tn + j) * M + bm + tm) = v0;
      *(float4*)(C + (size_t)(bn + tn + j) * M + bm + tm + 4) = v1;
    }
  } else {
    float bv[8];
#pragma unroll
    for (int j = 0; j < 8; j++) bv[j] = bias ? bias[bn + tn + j] : 0.f;
#pragma unroll
    for (int i = 0; i < 8; i++) {
      float4 v0 = make_float4(acc[i][0] + bv[0], acc[i][1] + bv[1], acc[i][2] + bv[2], acc[i][3] + bv[3]);
      float4 v1 = make_float4(acc[i][4] + bv[4], acc[i][5] + bv[5], acc[i][6] + bv[6], acc[i][7] + bv[7]);
      *(float4*)(C + (size_t)(bm + tm + i) * N + bn + tn) = v0;
      *(float4*)(C + (size_t)(bm + tm + i) * N + bn + tn + 4) = v1;
    }
  }
}

// ------------------------------------------------------------- LSTM layer ----
// Grid: 32 WGs = dir(2) x g(16). WG (d,g) owns h-units [g*16, g*16+16) i.e.
// gate rows q*256 + g*16 + u for q=0..3 (64 rows), ALL 16 batches.
// Weights LDS-stationary (64KB fp32). h exchanged via Hbuf with RELAXED
// agent-scope atomics only; per-WG tag words signal step completion.
// Gin layout: [n=d*1024+row][m=t*16+b]  (TRANS gemm output)
// Hout layout: [(t*16+b)*512 + d*256 + unit]
// Hbuf layout: [d][parity][unit][b]  (2*2*256*16 floats)
// tags layout: [d][16]
__global__ __launch_bounds__(512) void k_lstm(const float* __restrict__ Gin,
                                              const float* __restrict__ whh,
                                              float* __restrict__ Hout,
                                              float* __restrict__ Hbuf,
                                              int* __restrict__ tags) {
  const int d = blockIdx.x >> 4;
  const int g = blockIdx.x & 15;
  const int tid = threadIdx.x;
  __shared__ float whT[256][65];                 // whT[k][local_row]
  __shared__ __align__(16) float hs[256][16];    // h_prev [k][b]
  __shared__ float gacc[8][64][17];              // partial sums per k-chunk wave

  // load recurrent weights (transposed) into LDS, once
  for (int idx = tid; idx < 64 * 256; idx += 512) {
    int lr = idx >> 8, k = idx & 255;
    int grow = ((lr >> 4) << 8) + (g << 4) + (lr & 15);
    whT[k][lr] = whh[(size_t)((d << 10) + grow) * 256 + k];
  }
  float* hsf = &hs[0][0];
  float c_reg = 0.f;                             // cell state for (u=tid>>4, b=tid&15), tid<256
  int* mytags = tags + (d << 4);
  const int wv = tid >> 6, r = tid & 63;
  const int kb = wv * 32;
  const int ub = tid >> 4;                       // u for tid<256
  const int bb = tid & 15;

  for (int it = 0; it < 256; ++it) {
    const int step = d ? (255 - it) : it;

    // ---- prefetch Gin for this step (independent of h) ----
    float gin[4];
    if (tid < 256) {
#pragma unroll
      for (int q = 0; q < 4; ++q) {
        int grow = (q << 8) + (g << 4) + ub;
        gin[q] = Gin[(size_t)((d << 10) + grow) * 4096 + (step << 4) + bb];
      }
    }

    // ---- wait for previous step's h, stage into LDS ----
    if (it == 0) {
      for (int i = tid; i < 4096; i += 512) hsf[i] = 0.f;
    } else {
      if (tid < 16) {
        while (__hip_atomic_load(&mytags[tid], __ATOMIC_RELAXED, __HIP_MEMORY_SCOPE_AGENT) < it)
          __builtin_amdgcn_s_sleep(1);
      }
      __syncthreads();
      const float* src = Hbuf + (size_t)((d << 1) + ((it - 1) & 1)) * 4096;
      for (int i = tid; i < 4096; i += 512)
        hsf[i] = __hip_atomic_load(src + i, __ATOMIC_RELAXED, __HIP_MEMORY_SCOPE_AGENT);
    }
    __syncthreads();

    // ---- partial matvec: wave wv covers k in [kb, kb+32) ----
    float acc[16];
#pragma unroll
    for (int b = 0; b < 16; b++) acc[b] = 0.f;
#pragma unroll 4
    for (int k = kb; k < kb + 32; ++k) {
      float w = whT[k][r];
      const float4* hp = reinterpret_cast<const float4*>(&hs[k][0]);
      float4 h0 = hp[0], h1 = hp[1], h2 = hp[2], h3 = hp[3];
      acc[0]  += w * h0.x; acc[1]  += w * h0.y; acc[2]  += w * h0.z; acc[3]  += w * h0.w;
      acc[4]  += w * h1.x; acc[5]  += w * h1.y; acc[6]  += w * h1.z; acc[7]  += w * h1.w;
      acc[8]  += w * h2.x; acc[9]  += w * h2.y; acc[10] += w * h2.z; acc[11] += w * h2.w;
      acc[12] += w * h3.x; acc[13] += w * h3.y; acc[14] += w * h3.z; acc[15] += w * h3.w;
    }
#pragma unroll
    for (int b = 0; b < 16; b++) gacc[wv][r][b] = acc[b];
    __syncthreads();

    // ---- reduce 8 partials + Gin, nonlinearity, state update ----
    if (tid < 256) {
      float gate[4];
#pragma unroll
      for (int q = 0; q < 4; ++q) {
        int lr = (q << 4) + ub;
        float s = gin[q];
#pragma unroll
        for (int p = 0; p < 8; p++) s += gacc[p][lr][bb];
        gate[q] = s;
      }
      float ct = sigm(gate[1]) * c_reg + sigm(gate[0]) * tanhf(gate[2]);
      c_reg = ct;
      float h = sigm(gate[3]) * tanhf(ct);
      int unit = (g << 4) + ub;
      __hip_atomic_store(Hbuf + (size_t)((d << 1) + (it & 1)) * 4096 + (unit << 4) + bb, h,
                         __ATOMIC_RELAXED, __HIP_MEMORY_SCOPE_AGENT);
      Hout[(size_t)((step << 4) + bb) * 512 + (d << 8) + unit] = h;
    }
    // __syncthreads drains vmcnt(0) per-wave before s_barrier => all h stores
    // of this WG are at the LLC coherence point (sc1) when we pass it.
    __syncthreads();
    if (tid == 0) {
      asm volatile("" ::: "memory");
      __hip_atomic_store(&mytags[g], it + 1, __ATOMIC_RELAXED, __HIP_MEMORY_SCOPE_AGENT);
    }
  }
}

// ------------------------------------------------------------- attention ----
// scores[b][i][j] = sum_h va[h]*tanh(P[i*16+b][h] + Cc[j*16+b][h])
// out[0 .. 1M)   = scores (float)
// out[1M .. 2M)  = predictions (float 0/1) ; sigmoid(x)>=0.5 <=> x>=0
__global__ __launch_bounds__(256) void k_attn(const float* __restrict__ P,
                                              const float* __restrict__ Cc,
                                              const float* __restrict__ va,
                                              float* __restrict__ out) {
  const int b = blockIdx.x & 15, i = blockIdx.x >> 4;
  __shared__ float pv[128], vv[128];
  const int t = threadIdx.x;
  if (t < 128) {
    pv[t] = P[(size_t)((i << 4) + b) * 128 + t];
    vv[t] = va[t];
  }
  __syncthreads();
  const float4* c4 = reinterpret_cast<const float4*>(Cc + (size_t)((t << 4) + b) * 128);
  float acc = 0.f;
#pragma unroll 8
  for (int hh = 0; hh < 32; ++hh) {
    float4 cv = c4[hh];
    int h = hh << 2;
    acc += vv[h]     * tanhf(pv[h]     + cv.x);
    acc += vv[h + 1] * tanhf(pv[h + 1] + cv.y);
    acc += vv[h + 2] * tanhf(pv[h + 2] + cv.z);
    acc += vv[h + 3] * tanhf(pv[h + 3] + cv.w);
  }
  size_t o = ((size_t)b << 16) + ((size_t)i << 8) + (size_t)t;
  out[o] = acc;
  out[(1u << 20) + o] = (acc >= 0.f) ? 1.f : 0.f;
}

// --------------------------------------------------------------- launch ----
extern "C" void kernel_launch(void* const* d_in, const int* in_sizes, int n_in,
                              void* d_out, int out_size, void* d_ws, size_t ws_size,
                              hipStream_t stream) {
  const int*   concepts = (const int*)d_in[0];
  // d_in[1] = concepts_lengths (all == S, unused)
  const float* emb  = (const float*)d_in[2];
  const float* w_ih = (const float*)d_in[3];   // [2][2][1024][512]
  const float* w_hh = (const float*)d_in[4];   // [2][2][1024][256]
  const float* bias = (const float*)d_in[5];   // [2][2][1024]
  const float* Ua   = (const float*)d_in[6];   // [128][512]
  const float* Wa   = (const float*)d_in[7];   // [128][512]
  const float* va   = (const float*)d_in[8];   // [1][128]
  float* out = (float*)d_out;
  float* ws  = (float*)d_ws;

  constexpr size_t OFF_X   = 0;
  constexpr size_t OFF_G   = OFF_X  + (size_t)M_ * E_;        //  2,097,152
  constexpr size_t OFF_H0  = OFF_G  + (size_t)M_ * 2048;      // 10,485,760
  constexpr size_t OFF_H1  = OFF_H0 + (size_t)M_ * 512;
  constexpr size_t OFF_P   = OFF_H1 + (size_t)M_ * 512;
  constexpr size_t OFF_C   = OFF_P  + (size_t)M_ * HM_;
  constexpr size_t OFF_HB  = OFF_C  + (size_t)M_ * HM_;
  constexpr size_t OFF_TAG = OFF_HB + 2 * 2 * 256 * 16;

  float* X  = ws + OFF_X;
  float* G  = ws + OFF_G;
  float* H0 = ws + OFF_H0;
  float* H1 = ws + OFF_H1;
  float* Pm = ws + OFF_P;
  float* Cm = ws + OFF_C;
  float* Hb = ws + OFF_HB;
  int*   tags = (int*)(ws + OFF_TAG);          // [layer][d][16]

  hipMemsetAsync(tags, 0, 2 * 2 * 16 * sizeof(int), stream);

  k_gather<<<M_, 128, 0, stream>>>(concepts, emb, X);

  // layer 0
  k_gemm<true><<<dim3(32, 16), 256, 0, stream>>>(X, w_ih, bias, G, M_, 2048, 512);
  k_lstm<<<32, 512, 0, stream>>>(G, w_hh, H0, Hb, tags);

  // layer 1
  k_gemm<true><<<dim3(32, 16), 256, 0, stream>>>(H0, w_ih + (size_t)2048 * 512, bias + 2048,
                                                 G, M_, 2048, 512);
  k_lstm<<<32, 512, 0, stream>>>(G, w_hh + (size_t)2048 * 256, H1, Hb, tags + 32);

  // attention projections
  k_gemm<false><<<dim3(32, 1), 256, 0, stream>>>(H1, Ua, nullptr, Pm, M_, HM_, 512);
  k_gemm<false><<<dim3(32, 1), 256, 0, stream>>>(H1, Wa, nullptr, Cm, M_, HM_, 512);

  // fused pairwise scores + predictions
  k_attn<<<M_, 256, 0, stream>>>(Pm, Cm, va, out);
}

// Round 3
// 3154.520 us; speedup vs baseline: 2.1437x; 1.2523x over previous
//
#include <hip/hip_runtime.h>

// ---------------------------------------------------------------------------
// HeadsSelection: emb-gather -> 2x bidirectional LSTM -> additive attention
// S=256, B=16, V=20000, E=512, H=256, L=2, HM=128
// Round 3: MFMA recurrence in split-bf16 (hi+lo planes, 3-product Ootomo
// scheme => ~2^-17 relative error, fp32-class). Weights live in VGPRs
// (64 regs/lane, loaded once). h exchanged as packed {bf16_hi,bf16_lo}
// dwords via relaxed agent-scope atomics (R2's proven publish pattern).
// Per-WG step cost: 24 MFMA + 64 v_perm + tiny LDS epilogue.
// ---------------------------------------------------------------------------

#define S_    256
#define B_    16
#define E_    512
#define H_    256
#define HM_   128
#define M_    4096   // S*B

typedef __attribute__((ext_vector_type(8))) short short8;
typedef __attribute__((ext_vector_type(4))) float f32x4;

__device__ __forceinline__ float sigm(float x) { return 1.f / (1.f + __expf(-x)); }
__device__ __forceinline__ float tanh_fast(float x) {
  x = fminf(fmaxf(x, -15.f), 15.f);
  float e = __expf(2.f * x);
  return (e - 1.f) / (e + 1.f);
}
__device__ __forceinline__ unsigned short f2bf(float f) {
  unsigned u = __float_as_uint(f);
  u += 0x7FFFu + ((u >> 16) & 1u);
  return (unsigned short)(u >> 16);
}
__device__ __forceinline__ float bf2f(unsigned short s) {
  return __uint_as_float(((unsigned)s) << 16);
}

// ---------------------------------------------------------------- gather ----
__global__ void k_gather(const int* __restrict__ concepts, const float* __restrict__ emb,
                         float* __restrict__ X) {
  int m = blockIdx.x;                       // m = s*16 + b
  int tok = concepts[m];
  const float4* src = reinterpret_cast<const float4*>(emb + (size_t)tok * E_);
  float4* dst = reinterpret_cast<float4*>(X + (size_t)m * E_);
  for (int i = threadIdx.x; i < E_ / 4; i += blockDim.x) dst[i] = src[i];
}

// ------------------------------------------------------------------ GEMM ----
// C[m][n] = sum_k A[m][k] * W[n][k] + bias[n]
// TRANS: store C[n*M + m]; else C[m*N + n]
template <bool TRANS>
__global__ __launch_bounds__(256) void k_gemm(const float* __restrict__ A,
                                              const float* __restrict__ W,
                                              const float* __restrict__ bias,
                                              float* __restrict__ C,
                                              int M, int N, int K) {
  __shared__ __align__(16) float As[16][132];
  __shared__ __align__(16) float Ws[16][132];
  const int bm = blockIdx.x * 128, bn = blockIdx.y * 128;
  const int tid = threadIdx.x;
  const int tm = (tid >> 4) * 8, tn = (tid & 15) * 8;
  float acc[8][8];
#pragma unroll
  for (int i = 0; i < 8; i++)
#pragma unroll
    for (int j = 0; j < 8; j++) acc[i][j] = 0.f;

  const int lr = tid >> 1, lk = (tid & 1) * 8;
  for (int k0 = 0; k0 < K; k0 += 16) {
    float4 a0 = *(const float4*)(A + (size_t)(bm + lr) * K + k0 + lk);
    float4 a1 = *(const float4*)(A + (size_t)(bm + lr) * K + k0 + lk + 4);
    float4 w0 = *(const float4*)(W + (size_t)(bn + lr) * K + k0 + lk);
    float4 w1 = *(const float4*)(W + (size_t)(bn + lr) * K + k0 + lk + 4);
    As[lk + 0][lr] = a0.x; As[lk + 1][lr] = a0.y; As[lk + 2][lr] = a0.z; As[lk + 3][lr] = a0.w;
    As[lk + 4][lr] = a1.x; As[lk + 5][lr] = a1.y; As[lk + 6][lr] = a1.z; As[lk + 7][lr] = a1.w;
    Ws[lk + 0][lr] = w0.x; Ws[lk + 1][lr] = w0.y; Ws[lk + 2][lr] = w0.z; Ws[lk + 3][lr] = w0.w;
    Ws[lk + 4][lr] = w1.x; Ws[lk + 5][lr] = w1.y; Ws[lk + 6][lr] = w1.z; Ws[lk + 7][lr] = w1.w;
    __syncthreads();
#pragma unroll
    for (int k = 0; k < 16; k++) {
      float4 av0 = *(const float4*)&As[k][tm];
      float4 av1 = *(const float4*)&As[k][tm + 4];
      float4 wv0 = *(const float4*)&Ws[k][tn];
      float4 wv1 = *(const float4*)&Ws[k][tn + 4];
      float a[8] = {av0.x, av0.y, av0.z, av0.w, av1.x, av1.y, av1.z, av1.w};
      float w[8] = {wv0.x, wv0.y, wv0.z, wv0.w, wv1.x, wv1.y, wv1.z, wv1.w};
#pragma unroll
      for (int i = 0; i < 8; i++)
#pragma unroll
        for (int j = 0; j < 8; j++) acc[i][j] += a[i] * w[j];
    }
    __syncthreads();
  }

  if (TRANS) {
#pragma unroll
    for (int j = 0; j < 8; j++) {
      float bv = bias ? bias[bn + tn + j] : 0.f;
      float4 v0 = make_float4(acc[0][j] + bv, acc[1][j] + bv, acc[2][j] + bv, acc[3][j] + bv);
      float4 v1 = make_float4(acc[4][j] + bv, acc[5][j] + bv, acc[6][j] + bv, acc[7][j] + bv);
      *(float4*)(C + (size_t)(bn + tn + j) * M + bm + tm) = v0;
      *(float4*)(C + (size_t)(bn + tn + j) * M + bm + tm + 4) = v1;
    }
  } else {
    float bv[8];
#pragma unroll
    for (int j = 0; j < 8; j++) bv[j] = bias ? bias[bn + tn + j] : 0.f;
#pragma unroll
    for (int i = 0; i < 8; i++) {
      float4 v0 = make_float4(acc[i][0] + bv[0], acc[i][1] + bv[1], acc[i][2] + bv[2], acc[i][3] + bv[3]);
      float4 v1 = make_float4(acc[i][4] + bv[4], acc[i][5] + bv[5], acc[i][6] + bv[6], acc[i][7] + bv[7]);
      *(float4*)(C + (size_t)(bm + tm + i) * N + bn + tn) = v0;
      *(float4*)(C + (size_t)(bm + tm + i) * N + bn + tn + 4) = v1;
    }
  }
}

// ------------------------------------------------------------- LSTM layer ----
// Grid: 32 WGs = dir(2) x g(16), 256 threads (4 waves). Wave q computes gate q
// (rows q*256 + g*16 + [0,16)) for all 16 batches via MFMA 16x16x32 bf16:
//   A = whh rows, split bf16 hi/lo, resident in VGPRs (loaded once).
//   B = h_prev, read from Hbuf as packed {lo16=hi-bf16, hi16=lo-bf16} dwords.
//   acc = Ahi*Bhi + Ahi*Blo + Alo*Bhi  (3 parallel MFMA chains)
// Gin layout: [n=d*1024+row][m=t*16+b]; Hout: [(t*16+b)*512 + d*256 + unit]
// Hbuf: [d][parity][b][unit] packed dwords; tags: [d][16]
__global__ __launch_bounds__(256) void k_lstm(const float* __restrict__ Gin,
                                              const float* __restrict__ whh,
                                              float* __restrict__ Hout,
                                              unsigned int* __restrict__ Hbuf,
                                              int* __restrict__ tags) {
  const int d = blockIdx.x >> 4;
  const int g = blockIdx.x & 15;
  const int tid = threadIdx.x;
  const int q = tid >> 6;          // wave index = gate index (i,f,g,o)
  const int lane = tid & 63;
  const int bcol = lane & 15;      // MFMA A row m / C col n
  const int quad = lane >> 4;      // MFMA k-group / C row group
  const int u_e = tid & 15;        // epilogue: unit (fast, for Hout coalescing)
  const int b_e = tid >> 4;        // epilogue: batch
  __shared__ __align__(16) float Lg[4][16][24];   // [gate][b][unit(+pad)]
  int* mytags = tags + (d << 4);

  // ---- one-time: A fragments (whh) into VGPRs, split bf16 main+residual ----
  unsigned int Am[8][4], Ar[8][4];
  {
    const float* wrow = whh + (size_t)((d << 10) + (q << 8) + (g << 4) + bcol) * 256;
#pragma unroll
    for (int s = 0; s < 8; ++s) {
      float w[8];
      *(float4*)&w[0] = *(const float4*)(wrow + s * 32 + quad * 8);
      *(float4*)&w[4] = *(const float4*)(wrow + s * 32 + quad * 8 + 4);
#pragma unroll
      for (int j = 0; j < 4; ++j) {
        unsigned short m0 = f2bf(w[2 * j]), m1 = f2bf(w[2 * j + 1]);
        unsigned short r0 = f2bf(w[2 * j] - bf2f(m0));
        unsigned short r1 = f2bf(w[2 * j + 1] - bf2f(m1));
        Am[s][j] = (unsigned)m0 | ((unsigned)m1 << 16);
        Ar[s][j] = (unsigned)r0 | ((unsigned)r1 << 16);
      }
    }
  }

  float c_reg = 0.f;
  for (int it = 0; it < 256; ++it) {
    const int step = d ? (255 - it) : it;

    // ---- Gin prefetch (independent of h; ~1500cy of slack before use) ----
    float gin[4];
#pragma unroll
    for (int qq = 0; qq < 4; ++qq)
      gin[qq] = Gin[(size_t)((d << 10) + (qq << 8) + (g << 4) + u_e) * 4096 + (step << 4) + b_e];

    // ---- wait for peers' previous step ----
    if (it > 0 && tid < 16) {
      while (__hip_atomic_load(&mytags[tid], __ATOMIC_RELAXED, __HIP_MEMORY_SCOPE_AGENT) < it)
        __builtin_amdgcn_s_sleep(1);
    }
    __syncthreads();

    f32x4 acc0 = {0.f, 0.f, 0.f, 0.f}, acc1 = acc0, acc2 = acc0;
    if (it > 0) {
      // B loads: lane reads h[k = s*32+quad*8+j][bcol] as packed dwords
      const unsigned long long* hb =
          (const unsigned long long*)(Hbuf + ((size_t)((d << 1) + ((it - 1) & 1)) << 12)) +
          (bcol << 7) + (quad << 2);
      unsigned long long hv[32];
#pragma unroll
      for (int s = 0; s < 8; ++s)
#pragma unroll
        for (int j = 0; j < 4; ++j)
          hv[s * 4 + j] =
              __hip_atomic_load(hb + (s << 4) + j, __ATOMIC_RELAXED, __HIP_MEMORY_SCOPE_AGENT);
#pragma unroll
      for (int s = 0; s < 8; ++s) {
        union { unsigned int u[4]; short8 v; } Bm, Br, Amu, Aru;
#pragma unroll
        for (int j = 0; j < 4; ++j) {
          unsigned int d0 = (unsigned int)hv[s * 4 + j];
          unsigned int d1 = (unsigned int)(hv[s * 4 + j] >> 32);
          Bm.u[j] = __builtin_amdgcn_perm(d1, d0, 0x05040100u);  // main bf16 (low16s)
          Br.u[j] = __builtin_amdgcn_perm(d1, d0, 0x07060302u);  // residual bf16 (high16s)
          Amu.u[j] = Am[s][j];
          Aru.u[j] = Ar[s][j];
        }
        acc0 = __builtin_amdgcn_mfma_f32_16x16x32_bf16(Amu.v, Bm.v, acc0, 0, 0, 0);
        acc1 = __builtin_amdgcn_mfma_f32_16x16x32_bf16(Amu.v, Br.v, acc1, 0, 0, 0);
        acc2 = __builtin_amdgcn_mfma_f32_16x16x32_bf16(Aru.v, Bm.v, acc2, 0, 0, 0);
      }
    }
    // ---- gate tile -> LDS (C layout: col=lane&15=b, row=quad*4+i=unit) ----
    {
      f32x4 t = acc0 + acc1 + acc2;
      int u0 = quad << 2;
      *(float4*)&Lg[q][bcol][u0] = make_float4(t[0], t[1], t[2], t[3]);
    }
    __syncthreads();

    // ---- nonlinearity + state update (all 256 threads: unit u_e, batch b_e) ----
    {
      float gi = Lg[0][b_e][u_e] + gin[0];
      float gf = Lg[1][b_e][u_e] + gin[1];
      float gg = Lg[2][b_e][u_e] + gin[2];
      float go = Lg[3][b_e][u_e] + gin[3];
      float ct = sigm(gf) * c_reg + sigm(gi) * tanh_fast(gg);
      c_reg = ct;
      float h = sigm(go) * tanh_fast(ct);
      unsigned short hm = f2bf(h);
      unsigned short hr = f2bf(h - bf2f(hm));
      unsigned int hp = (unsigned)hm | ((unsigned)hr << 16);
      __hip_atomic_store(Hbuf + ((size_t)((d << 1) + (it & 1)) << 12) + (b_e << 8) + (g << 4) + u_e,
                         hp, __ATOMIC_RELAXED, __HIP_MEMORY_SCOPE_AGENT);
      Hout[(size_t)((step << 4) + b_e) * 512 + (d << 8) + (g << 4) + u_e] = h;
    }
    // __syncthreads: each wave drains vmcnt(0) before s_barrier => all stores
    // of this WG are at the LLC when tid 0 publishes the tag.
    __syncthreads();
    if (tid == 0)
      __hip_atomic_store(&mytags[g], it + 1, __ATOMIC_RELAXED, __HIP_MEMORY_SCOPE_AGENT);
  }
}

// ------------------------------------------------------------- attention ----
// scores[b][i][j] = sum_h va[h]*tanh(P[i*16+b][h] + Cc[j*16+b][h])
// out[0 .. 1M) = scores; out[1M .. 2M) = predictions (sigmoid>=0.5 <=> x>=0)
__global__ __launch_bounds__(256) void k_attn(const float* __restrict__ P,
                                              const float* __restrict__ Cc,
                                              const float* __restrict__ va,
                                              float* __restrict__ out) {
  const int b = blockIdx.x & 15, i = blockIdx.x >> 4;
  __shared__ float pv[128], vv[128];
  const int t = threadIdx.x;
  if (t < 128) {
    pv[t] = P[(size_t)((i << 4) + b) * 128 + t];
    vv[t] = va[t];
  }
  __syncthreads();
  const float4* c4 = reinterpret_cast<const float4*>(Cc + (size_t)((t << 4) + b) * 128);
  float acc = 0.f;
#pragma unroll 8
  for (int hh = 0; hh < 32; ++hh) {
    float4 cv = c4[hh];
    int h = hh << 2;
    acc += vv[h]     * tanhf(pv[h]     + cv.x);
    acc += vv[h + 1] * tanhf(pv[h + 1] + cv.y);
    acc += vv[h + 2] * tanhf(pv[h + 2] + cv.z);
    acc += vv[h + 3] * tanhf(pv[h + 3] + cv.w);
  }
  size_t o = ((size_t)b << 16) + ((size_t)i << 8) + (size_t)t;
  out[o] = acc;
  out[(1u << 20) + o] = (acc >= 0.f) ? 1.f : 0.f;
}

// --------------------------------------------------------------- launch ----
extern "C" void kernel_launch(void* const* d_in, const int* in_sizes, int n_in,
                              void* d_out, int out_size, void* d_ws, size_t ws_size,
                              hipStream_t stream) {
  const int*   concepts = (const int*)d_in[0];
  // d_in[1] = concepts_lengths (all == S, unused)
  const float* emb  = (const float*)d_in[2];
  const float* w_ih = (const float*)d_in[3];   // [2][2][1024][512]
  const float* w_hh = (const float*)d_in[4];   // [2][2][1024][256]
  const float* bias = (const float*)d_in[5];   // [2][2][1024]
  const float* Ua   = (const float*)d_in[6];   // [128][512]
  const float* Wa   = (const float*)d_in[7];   // [128][512]
  const float* va   = (const float*)d_in[8];   // [1][128]
  float* out = (float*)d_out;
  float* ws  = (float*)d_ws;

  constexpr size_t OFF_X   = 0;
  constexpr size_t OFF_G   = OFF_X  + (size_t)M_ * E_;
  constexpr size_t OFF_H0  = OFF_G  + (size_t)M_ * 2048;
  constexpr size_t OFF_H1  = OFF_H0 + (size_t)M_ * 512;
  constexpr size_t OFF_P   = OFF_H1 + (size_t)M_ * 512;
  constexpr size_t OFF_C   = OFF_P  + (size_t)M_ * HM_;
  constexpr size_t OFF_HB  = OFF_C  + (size_t)M_ * HM_;   // 2*2*4096 dwords
  constexpr size_t OFF_TAG = OFF_HB + 2 * 2 * 4096;

  float* X  = ws + OFF_X;
  float* G  = ws + OFF_G;
  float* H0 = ws + OFF_H0;
  float* H1 = ws + OFF_H1;
  float* Pm = ws + OFF_P;
  float* Cm = ws + OFF_C;
  unsigned int* Hb = (unsigned int*)(ws + OFF_HB);
  int* tags = (int*)(ws + OFF_TAG);            // [layer][dir][16]

  hipMemsetAsync(tags, 0, 2 * 2 * 16 * sizeof(int), stream);

  k_gather<<<M_, 128, 0, stream>>>(concepts, emb, X);

  // layer 0
  k_gemm<true><<<dim3(32, 16), 256, 0, stream>>>(X, w_ih, bias, G, M_, 2048, 512);
  k_lstm<<<32, 256, 0, stream>>>(G, w_hh, H0, Hb, tags);

  // layer 1
  k_gemm<true><<<dim3(32, 16), 256, 0, stream>>>(H0, w_ih + (size_t)2048 * 512, bias + 2048,
                                                 G, M_, 2048, 512);
  k_lstm<<<32, 256, 0, stream>>>(G, w_hh + (size_t)2048 * 256, H1, Hb, tags + 32);

  // attention projections
  k_gemm<false><<<dim3(32, 1), 256, 0, stream>>>(H1, Ua, nullptr, Pm, M_, HM_, 512);
  k_gemm<false><<<dim3(32, 1), 256, 0, stream>>>(H1, Wa, nullptr, Cm, M_, HM_, 512);

  // fused pairwise scores + predictions
  k_attn<<<M_, 256, 0, stream>>>(Pm, Cm, va, out);
}

// Round 4
// 1895.435 us; speedup vs baseline: 3.5676x; 1.6643x over previous
//
#include <hip/hip_runtime.h>

// ---------------------------------------------------------------------------
// HeadsSelection: emb-gather -> 2x bidirectional LSTM -> additive attention
// S=256, B=16, V=20000, E=512, H=256, L=2, HM=128
// Round 4: single-round-trip LLC exchange for the recurrence.
//   Each h entry is a u64 {stamp: it+1, data: packed bf16 hi/lo} stored with
//   ONE relaxed agent-scope atomic. No tags, no fences, no producer-side
//   drain: the consumer's data load doubles as the readiness check (stamp
//   compare in registers, re-load only stale entries). h staged to LDS once
//   per WG (4 waves x 1024 entries), MFMA split-bf16 3-product as R3.
// ---------------------------------------------------------------------------

#define S_    256
#define B_    16
#define E_    512
#define H_    256
#define HM_   128
#define M_    4096   // S*B

typedef __attribute__((ext_vector_type(8))) short short8;
typedef __attribute__((ext_vector_type(4))) float f32x4;

__device__ __forceinline__ float sigm(float x) { return 1.f / (1.f + __expf(-x)); }
__device__ __forceinline__ float tanh_fast(float x) {
  x = fminf(fmaxf(x, -15.f), 15.f);
  float e = __expf(2.f * x);
  return (e - 1.f) / (e + 1.f);
}
__device__ __forceinline__ unsigned short f2bf(float f) {
  unsigned u = __float_as_uint(f);
  u += 0x7FFFu + ((u >> 16) & 1u);
  return (unsigned short)(u >> 16);
}
__device__ __forceinline__ float bf2f(unsigned short s) {
  return __uint_as_float(((unsigned)s) << 16);
}

// ---------------------------------------------------------------- gather ----
__global__ void k_gather(const int* __restrict__ concepts, const float* __restrict__ emb,
                         float* __restrict__ X) {
  int m = blockIdx.x;                       // m = s*16 + b
  int tok = concepts[m];
  const float4* src = reinterpret_cast<const float4*>(emb + (size_t)tok * E_);
  float4* dst = reinterpret_cast<float4*>(X + (size_t)m * E_);
  for (int i = threadIdx.x; i < E_ / 4; i += blockDim.x) dst[i] = src[i];
}

// ------------------------------------------------------------------ GEMM ----
// C[m][n] = sum_k A[m][k] * W[n][k] + bias[n]
// TRANS: store C[n*M + m]; else C[m*N + n]
template <bool TRANS>
__global__ __launch_bounds__(256) void k_gemm(const float* __restrict__ A,
                                              const float* __restrict__ W,
                                              const float* __restrict__ bias,
                                              float* __restrict__ C,
                                              int M, int N, int K) {
  __shared__ __align__(16) float As[16][132];
  __shared__ __align__(16) float Ws[16][132];
  const int bm = blockIdx.x * 128, bn = blockIdx.y * 128;
  const int tid = threadIdx.x;
  const int tm = (tid >> 4) * 8, tn = (tid & 15) * 8;
  float acc[8][8];
#pragma unroll
  for (int i = 0; i < 8; i++)
#pragma unroll
    for (int j = 0; j < 8; j++) acc[i][j] = 0.f;

  const int lr = tid >> 1, lk = (tid & 1) * 8;
  for (int k0 = 0; k0 < K; k0 += 16) {
    float4 a0 = *(const float4*)(A + (size_t)(bm + lr) * K + k0 + lk);
    float4 a1 = *(const float4*)(A + (size_t)(bm + lr) * K + k0 + lk + 4);
    float4 w0 = *(const float4*)(W + (size_t)(bn + lr) * K + k0 + lk);
    float4 w1 = *(const float4*)(W + (size_t)(bn + lr) * K + k0 + lk + 4);
    As[lk + 0][lr] = a0.x; As[lk + 1][lr] = a0.y; As[lk + 2][lr] = a0.z; As[lk + 3][lr] = a0.w;
    As[lk + 4][lr] = a1.x; As[lk + 5][lr] = a1.y; As[lk + 6][lr] = a1.z; As[lk + 7][lr] = a1.w;
    Ws[lk + 0][lr] = w0.x; Ws[lk + 1][lr] = w0.y; Ws[lk + 2][lr] = w0.z; Ws[lk + 3][lr] = w0.w;
    Ws[lk + 4][lr] = w1.x; Ws[lk + 5][lr] = w1.y; Ws[lk + 6][lr] = w1.z; Ws[lk + 7][lr] = w1.w;
    __syncthreads();
#pragma unroll
    for (int k = 0; k < 16; k++) {
      float4 av0 = *(const float4*)&As[k][tm];
      float4 av1 = *(const float4*)&As[k][tm + 4];
      float4 wv0 = *(const float4*)&Ws[k][tn];
      float4 wv1 = *(const float4*)&Ws[k][tn + 4];
      float a[8] = {av0.x, av0.y, av0.z, av0.w, av1.x, av1.y, av1.z, av1.w};
      float w[8] = {wv0.x, wv0.y, wv0.z, wv0.w, wv1.x, wv1.y, wv1.z, wv1.w};
#pragma unroll
      for (int i = 0; i < 8; i++)
#pragma unroll
        for (int j = 0; j < 8; j++) acc[i][j] += a[i] * w[j];
    }
    __syncthreads();
  }

  if (TRANS) {
#pragma unroll
    for (int j = 0; j < 8; j++) {
      float bv = bias ? bias[bn + tn + j] : 0.f;
      float4 v0 = make_float4(acc[0][j] + bv, acc[1][j] + bv, acc[2][j] + bv, acc[3][j] + bv);
      float4 v1 = make_float4(acc[4][j] + bv, acc[5][j] + bv, acc[6][j] + bv, acc[7][j] + bv);
      *(float4*)(C + (size_t)(bn + tn + j) * M + bm + tm) = v0;
      *(float4*)(C + (size_t)(bn + tn + j) * M + bm + tm + 4) = v1;
    }
  } else {
    float bv[8];
#pragma unroll
    for (int j = 0; j < 8; j++) bv[j] = bias ? bias[bn + tn + j] : 0.f;
#pragma unroll
    for (int i = 0; i < 8; i++) {
      float4 v0 = make_float4(acc[i][0] + bv[0], acc[i][1] + bv[1], acc[i][2] + bv[2], acc[i][3] + bv[3]);
      float4 v1 = make_float4(acc[i][4] + bv[4], acc[i][5] + bv[5], acc[i][6] + bv[6], acc[i][7] + bv[7]);
      *(float4*)(C + (size_t)(bm + tm + i) * N + bn + tn) = v0;
      *(float4*)(C + (size_t)(bm + tm + i) * N + bn + tn + 4) = v1;
    }
  }
}

// ------------------------------------------------------------- LSTM layer ----
// Grid: 32 WGs = dir(2) x g(16), 256 threads (4 waves). Wave q = gate q.
// A = whh rows split bf16 hi/lo in VGPRs. B = h_prev from Hbuf u64 entries
// {stamp,packed}, staged via LDS hL[b*260+k]. C layout verified in R3.
// Gin: [n=d*1024+row][m=t*16+b]; Hout: [(t*16+b)*512 + d*256 + unit]
// Hbuf: [d][parity][b][unit] u64 entries.
__global__ __launch_bounds__(256) void k_lstm(const float* __restrict__ Gin,
                                              const float* __restrict__ whh,
                                              float* __restrict__ Hout,
                                              unsigned long long* __restrict__ Hbuf) {
  const int d = blockIdx.x >> 4;
  const int g = blockIdx.x & 15;
  const int tid = threadIdx.x;
  const int q = tid >> 6;          // wave index = gate index (i,f,g,o)
  const int lane = tid & 63;
  const int bcol = lane & 15;      // MFMA A row m / C col n (batch)
  const int quad = lane >> 4;      // MFMA k-group / C row group
  const int u_e = tid & 15;        // epilogue: unit
  const int b_e = tid >> 4;        // epilogue: batch
  __shared__ unsigned int hL[16 * 260];           // packed h: [b]*260 + [k]
  __shared__ __align__(16) float Lg[4][16][24];   // [gate][b][unit(+pad)]

  // ---- one-time: A fragments (whh) into VGPRs, split bf16 main+residual ----
  unsigned int Am[8][4], Ar[8][4];
  {
    const float* wrow = whh + (size_t)((d << 10) + (q << 8) + (g << 4) + bcol) * 256;
#pragma unroll
    for (int s = 0; s < 8; ++s) {
      float w[8];
      *(float4*)&w[0] = *(const float4*)(wrow + s * 32 + quad * 8);
      *(float4*)&w[4] = *(const float4*)(wrow + s * 32 + quad * 8 + 4);
#pragma unroll
      for (int j = 0; j < 4; ++j) {
        unsigned short m0 = f2bf(w[2 * j]), m1 = f2bf(w[2 * j + 1]);
        unsigned short r0 = f2bf(w[2 * j] - bf2f(m0));
        unsigned short r1 = f2bf(w[2 * j + 1] - bf2f(m1));
        Am[s][j] = (unsigned)m0 | ((unsigned)m1 << 16);
        Ar[s][j] = (unsigned)r0 | ((unsigned)r1 << 16);
      }
    }
  }

  float c_reg = 0.f;
  for (int it = 0; it < 256; ++it) {
    const int step = d ? (255 - it) : it;

    // ---- Gin prefetch (independent of h) ----
    float gin[4];
#pragma unroll
    for (int qq = 0; qq < 4; ++qq)
      gin[qq] = Gin[(size_t)((d << 10) + (qq << 8) + (g << 4) + u_e) * 4096 + (step << 4) + b_e];

    // ---- stage h_prev: load u64 {stamp,data}, retry stale, write LDS ----
    if (it > 0) {
      const unsigned long long* src = Hbuf + ((size_t)((d << 1) + ((it - 1) & 1)) << 12);
      const unsigned int want = (unsigned int)it;
      const int base = (q << 10) + lane;           // wave q covers entries [q*1024, +1024)
      unsigned long long v[16];
#pragma unroll
      for (int c = 0; c < 16; ++c)
        v[c] = __hip_atomic_load(src + base + (c << 6), __ATOMIC_RELAXED,
                                 __HIP_MEMORY_SCOPE_AGENT);
      for (;;) {
        unsigned int badm = 0;
#pragma unroll
        for (int c = 0; c < 16; ++c)
          badm |= ((unsigned int)(v[c] >> 32) != want) ? (1u << c) : 0u;
        if (__ballot(badm != 0) == 0ull) break;
#pragma unroll
        for (int c = 0; c < 16; ++c)
          if (badm & (1u << c))
            v[c] = __hip_atomic_load(src + base + (c << 6), __ATOMIC_RELAXED,
                                     __HIP_MEMORY_SCOPE_AGENT);
      }
#pragma unroll
      for (int c = 0; c < 16; ++c) {
        int b = (q << 2) + (c >> 2);               // entry e = q*1024+c*64+lane = b*256+k
        int k = ((c & 3) << 6) + lane;
        hL[b * 260 + k] = (unsigned int)v[c];
      }
    }
    __syncthreads();

    // ---- B fragments from LDS, 3-product split MFMA ----
    f32x4 acc0 = {0.f, 0.f, 0.f, 0.f}, acc1 = acc0, acc2 = acc0;
    if (it > 0) {
#pragma unroll
      for (int s = 0; s < 8; ++s) {
        const unsigned int* p = &hL[bcol * 260 + (s << 5) + (quad << 3)];
        uint4 p0 = *(const uint4*)p;
        uint4 p1 = *(const uint4*)(p + 4);
        union { unsigned int u[4]; short8 v; } Bm, Br, Amu, Aru;
        Bm.u[0] = __builtin_amdgcn_perm(p0.y, p0.x, 0x05040100u);
        Br.u[0] = __builtin_amdgcn_perm(p0.y, p0.x, 0x07060302u);
        Bm.u[1] = __builtin_amdgcn_perm(p0.w, p0.z, 0x05040100u);
        Br.u[1] = __builtin_amdgcn_perm(p0.w, p0.z, 0x07060302u);
        Bm.u[2] = __builtin_amdgcn_perm(p1.y, p1.x, 0x05040100u);
        Br.u[2] = __builtin_amdgcn_perm(p1.y, p1.x, 0x07060302u);
        Bm.u[3] = __builtin_amdgcn_perm(p1.w, p1.z, 0x05040100u);
        Br.u[3] = __builtin_amdgcn_perm(p1.w, p1.z, 0x07060302u);
#pragma unroll
        for (int j = 0; j < 4; ++j) { Amu.u[j] = Am[s][j]; Aru.u[j] = Ar[s][j]; }
        acc0 = __builtin_amdgcn_mfma_f32_16x16x32_bf16(Amu.v, Bm.v, acc0, 0, 0, 0);
        acc1 = __builtin_amdgcn_mfma_f32_16x16x32_bf16(Amu.v, Br.v, acc1, 0, 0, 0);
        acc2 = __builtin_amdgcn_mfma_f32_16x16x32_bf16(Aru.v, Bm.v, acc2, 0, 0, 0);
      }
    }
    // ---- gate tile -> LDS (C layout: col=lane&15=batch, row=quad*4+i=unit) ----
    {
      f32x4 t = acc0 + acc1 + acc2;
      *(float4*)&Lg[q][bcol][quad << 2] = make_float4(t[0], t[1], t[2], t[3]);
    }
    __syncthreads();

    // ---- nonlinearity + state update; fire-and-forget publish ----
    {
      float gi = Lg[0][b_e][u_e] + gin[0];
      float gf = Lg[1][b_e][u_e] + gin[1];
      float gg = Lg[2][b_e][u_e] + gin[2];
      float go = Lg[3][b_e][u_e] + gin[3];
      float ct = sigm(gf) * c_reg + sigm(gi) * tanh_fast(gg);
      c_reg = ct;
      float h = sigm(go) * tanh_fast(ct);
      unsigned short hm = f2bf(h);
      unsigned short hr = f2bf(h - bf2f(hm));
      unsigned long long hp = ((unsigned long long)(unsigned int)(it + 1) << 32) |
                              (unsigned long long)(((unsigned)hr << 16) | (unsigned)hm);
      __hip_atomic_store(Hbuf + ((size_t)((d << 1) + (it & 1)) << 12) + (b_e << 8) + (g << 4) + u_e,
                         hp, __ATOMIC_RELAXED, __HIP_MEMORY_SCOPE_AGENT);
      Hout[(size_t)((step << 4) + b_e) * 512 + (d << 8) + (g << 4) + u_e] = h;
    }
    // no drain barrier: consumers validate stamps themselves.
  }
}

// ------------------------------------------------------------- attention ----
// scores[b][i][j] = sum_h va[h]*tanh(P[i*16+b][h] + Cc[j*16+b][h])
// out[0 .. 1M) = scores; out[1M .. 2M) = predictions (sigmoid>=0.5 <=> x>=0)
__global__ __launch_bounds__(256) void k_attn(const float* __restrict__ P,
                                              const float* __restrict__ Cc,
                                              const float* __restrict__ va,
                                              float* __restrict__ out) {
  const int b = blockIdx.x & 15, i = blockIdx.x >> 4;
  __shared__ float pv[128], vv[128];
  const int t = threadIdx.x;
  if (t < 128) {
    pv[t] = P[(size_t)((i << 4) + b) * 128 + t];
    vv[t] = va[t];
  }
  __syncthreads();
  const float4* c4 = reinterpret_cast<const float4*>(Cc + (size_t)((t << 4) + b) * 128);
  float acc = 0.f;
#pragma unroll 8
  for (int hh = 0; hh < 32; ++hh) {
    float4 cv = c4[hh];
    int h = hh << 2;
    acc += vv[h]     * tanhf(pv[h]     + cv.x);
    acc += vv[h + 1] * tanhf(pv[h + 1] + cv.y);
    acc += vv[h + 2] * tanhf(pv[h + 2] + cv.z);
    acc += vv[h + 3] * tanhf(pv[h + 3] + cv.w);
  }
  size_t o = ((size_t)b << 16) + ((size_t)i << 8) + (size_t)t;
  out[o] = acc;
  out[(1u << 20) + o] = (acc >= 0.f) ? 1.f : 0.f;
}

// --------------------------------------------------------------- launch ----
extern "C" void kernel_launch(void* const* d_in, const int* in_sizes, int n_in,
                              void* d_out, int out_size, void* d_ws, size_t ws_size,
                              hipStream_t stream) {
  const int*   concepts = (const int*)d_in[0];
  // d_in[1] = concepts_lengths (all == S, unused)
  const float* emb  = (const float*)d_in[2];
  const float* w_ih = (const float*)d_in[3];   // [2][2][1024][512]
  const float* w_hh = (const float*)d_in[4];   // [2][2][1024][256]
  const float* bias = (const float*)d_in[5];   // [2][2][1024]
  const float* Ua   = (const float*)d_in[6];   // [128][512]
  const float* Wa   = (const float*)d_in[7];   // [128][512]
  const float* va   = (const float*)d_in[8];   // [1][128]
  float* out = (float*)d_out;
  float* ws  = (float*)d_ws;

  constexpr size_t OFF_X   = 0;
  constexpr size_t OFF_G   = OFF_X  + (size_t)M_ * E_;
  constexpr size_t OFF_H0  = OFF_G  + (size_t)M_ * 2048;
  constexpr size_t OFF_H1  = OFF_H0 + (size_t)M_ * 512;
  constexpr size_t OFF_P   = OFF_H1 + (size_t)M_ * 512;
  constexpr size_t OFF_C   = OFF_P  + (size_t)M_ * HM_;
  constexpr size_t OFF_HB  = OFF_C  + (size_t)M_ * HM_;   // u64[2 layers][2d][2par][4096]

  float* X  = ws + OFF_X;
  float* G  = ws + OFF_G;
  float* H0 = ws + OFF_H0;
  float* H1 = ws + OFF_H1;
  float* Pm = ws + OFF_P;
  float* Cm = ws + OFF_C;
  unsigned long long* Hb0 = (unsigned long long*)(ws + OFF_HB);
  unsigned long long* Hb1 = Hb0 + 2 * 2 * 4096;

  k_gather<<<M_, 128, 0, stream>>>(concepts, emb, X);

  // layer 0
  k_gemm<true><<<dim3(32, 16), 256, 0, stream>>>(X, w_ih, bias, G, M_, 2048, 512);
  k_lstm<<<32, 256, 0, stream>>>(G, w_hh, H0, Hb0);

  // layer 1
  k_gemm<true><<<dim3(32, 16), 256, 0, stream>>>(H0, w_ih + (size_t)2048 * 512, bias + 2048,
                                                 G, M_, 2048, 512);
  k_lstm<<<32, 256, 0, stream>>>(G, w_hh + (size_t)2048 * 256, H1, Hb1);

  // attention projections
  k_gemm<false><<<dim3(32, 1), 256, 0, stream>>>(H1, Ua, nullptr, Pm, M_, HM_, 512);
  k_gemm<false><<<dim3(32, 1), 256, 0, stream>>>(H1, Wa, nullptr, Cm, M_, HM_, 512);

  // fused pairwise scores + predictions
  k_attn<<<M_, 256, 0, stream>>>(Pm, Cm, va, out);
}